// Round 1
// baseline (3813.080 us; speedup 1.0000x reference)
//
#include <hip/hip_runtime.h>
#include <cstdint>
#include <cstddef>

// ---------------- constants ----------------
#define H160   160
#define CHS    179200      // 7*160*160 (channel stride in seq / seqT)
#define HD     86          // h-74
#define GW     72          // grid width (72x72 points)
#define PG     5184        // 72*72
#define P66    4356        // 66*66
#define IDX146 21316       // 146*146
#define NVNH   5625        // 75*75
#define SELF_CAND 19687    // 3*5625 + 37*75 + 37
#define CHUNK  2625        // candidates per chunk (39375 = 15*2625)
#define NCHUNK 15
#define NBANK  21          // 2625 = 21*125
#define BANKLEN 125
#define INFF __int_as_float(0x7f800000)

// ---------------- k0: transpose seq -> seqT[pl][x][y] ----------------
__global__ void k0_transpose(const float* __restrict__ seq, float* __restrict__ seqT) {
  int pl = blockIdx.y;           // 0..20  (c*7+t)
  int x  = blockIdx.x;           // 0..159
  int y  = threadIdx.x;          // 0..159
  seqT[(pl * H160 + x) * H160 + y] = seq[(pl * H160 + y) * H160 + x];
}

// ---------------- init distances to +inf ----------------
__global__ void k_init(float* __restrict__ sd, int n) {
  int i = blockIdx.x * 256 + threadIdx.x;
  if (i < n) sd[i] = INFF;
}

// ---------------- k1: per-candidate boxed distance field (bitwise-replicates
// numpy: d = mean_c((win-seq_n)^2); box15 via sequential fp32 cumsum diffs) ----
__global__ __launch_bounds__(128) void k1_dist(const float* __restrict__ seqT,
                                               float* __restrict__ wsD, int chunkBase) {
  __shared__ float cs[HD][HD];   // row prefix sums
  __shared__ float col[HD][GW];  // column prefix sums of row-boxed
  int cand = chunkBase + (int)blockIdx.x;
  int ts = cand / NVNH;
  int rr = cand % NVNH;
  int vs = rr / 75;
  int hv = rr % 75;
  int t = threadIdx.x;
  if (t < HD) {
    int y = t;
    const float* pa = seqT + (ts * H160 + hv) * H160 + (vs + y);      // ch0, +x*160
    const float* pb = seqT + (3  * H160 + 37) * H160 + (37 + y);      // frame3 target
    float c0 = 0.f;
    for (int x = 0; x < HD; ++x) {
      int o = x * H160;
      float d0 = __fsub_rn(pa[o],            pb[o]);
      float d1 = __fsub_rn(pa[o + CHS],      pb[o + CHS]);
      float d2 = __fsub_rn(pa[o + 2 * CHS],  pb[o + 2 * CHS]);
      float s  = __fadd_rn(__fadd_rn(__fmul_rn(d0, d0), __fmul_rn(d1, d1)), __fmul_rn(d2, d2));
      float dd = __fdiv_rn(s, 3.0f);
      c0 = __fadd_rn(c0, dd);
      cs[y][x] = c0;
    }
  }
  __syncthreads();
  if (t < GW) {
    int j = t;
    float cc = 0.f;
    for (int r = 0; r < HD; ++r) {
      float v = (j == 0) ? cs[r][14] : __fsub_rn(cs[r][j + 14], cs[r][j - 1]);
      cc = __fadd_rn(cc, v);
      col[r][j] = cc;
    }
    float* D = wsD + (size_t)blockIdx.x * PG;
    for (int gy = 0; gy < GW; ++gy) {
      float v = (gy == 0) ? col[14][j] : __fsub_rn(col[gy + 14][j], col[gy - 1][j]);
      D[gy * GW + j] = v;
    }
  }
}

// ---------------- k2: banked top-14 update (strict-less insert == stable top_k) --
__global__ __launch_bounds__(64) void k2_topk(const float* __restrict__ wsD,
                                              float* __restrict__ sd, int* __restrict__ si,
                                              int chunkBase) {
  int pid = blockIdx.x * 64 + threadIdx.x;      // 5184 = 81*64
  int s = blockIdx.y;                           // bank
  float d[14]; int id[14];
#pragma unroll
  for (int k = 0; k < 14; ++k) { d[k] = sd[(s * 14 + k) * PG + pid]; id[k] = si[(s * 14 + k) * PG + pid]; }
  int gy = pid / GW, gx = pid % GW;
  for (int i = 0; i < BANKLEN; ++i) {
    int c = s * BANKLEN + i;
    float dist = wsD[(size_t)c * PG + pid];
    int cand = chunkBase + c;
    if (cand == SELF_CAND) continue;
    if (dist < d[13]) {
      int ts = cand / NVNH;
      int rr = cand % NVNH;
      int vs = rr / 75, hvv = rr % 75;
      int idx = ts * IDX146 + (gy + vs) * 146 + (gx + hvv);
#pragma unroll
      for (int j = 13; j >= 1; --j) {
        bool shift = dist < d[j - 1];
        bool here  = dist < d[j];
        float nv = shift ? d[j - 1]  : (here ? dist : d[j]);
        int   ni = shift ? id[j - 1] : (here ? idx  : id[j]);
        d[j] = nv; id[j] = ni;
      }
      if (dist < d[0]) { id[0] = idx; d[0] = dist; }
    }
  }
#pragma unroll
  for (int k = 0; k < 14; ++k) { sd[(s * 14 + k) * PG + pid] = d[k]; si[(s * 14 + k) * PG + pid] = id[k]; }
}

// ---------------- merge 21 sorted banks -> final 14 (tie-break by candidate time) --
__global__ __launch_bounds__(64) void k_merge(const float* __restrict__ sd,
                                              const int* __restrict__ si,
                                              int* __restrict__ fsi) {
  int pid = blockIdx.x * 64 + threadIdx.x;
  int gy = pid / GW, gx = pid % GW;
  int cur[NBANK];
  for (int s = 0; s < NBANK; ++s) cur[s] = 0;
  for (int o = 0; o < 14; ++o) {
    float bd = INFF; int bt = 0x7fffffff; int bs = 0; int bi = 0;
    for (int s = 0; s < NBANK; ++s) {
      if (cur[s] >= 14) continue;
      float dd = sd[(s * 14 + cur[s]) * PG + pid];
      int ii  = si[(s * 14 + cur[s]) * PG + pid];
      int ts = ii / IDX146; int rem = ii % IDX146;
      int pv = rem / 146, ph = rem % 146;
      int tt = (ts * 75 + (pv - gy)) * 75 + (ph - gx);
      if (dd < bd || (dd == bd && tt < bt)) { bd = dd; bt = tt; bs = s; bi = ii; }
    }
    fsi[o * PG + pid] = bi;
    cur[bs]++;
  }
}

// ---------------- k3: build x_f = [layers(147), wts(3)] per neighbor slot ----------
__global__ void k3_layers(const float* __restrict__ seq, const int* __restrict__ fsi,
                          float* __restrict__ X) {
  int n = blockIdx.y;                       // 0..14
  int p = blockIdx.x * 256 + threadIdx.x;
  if (p >= P66) return;
  int yo = p / 66, xo = p % 66;
  int y = yo + 6, x = xo + 6;
  float sv0 = seq[(0 * 7 + 3) * 25600 + (41 + y) * H160 + (41 + x)];
  float sv1 = seq[(1 * 7 + 3) * 25600 + (41 + y) * H160 + (41 + x)];
  float sv2 = seq[(2 * 7 + 3) * 25600 + (41 + y) * H160 + (41 + x)];
  float w0 = 0.f, w1 = 0.f, w2 = 0.f;
  for (int mv = 0; mv < 7; ++mv) {
    int dy = (y - mv) % 7; int gyy = y - dy;
    for (int mh = 0; mh < 7; ++mh) {
      int dx = (x - mh) % 7; int gxx = x - dx;
      int q = mv * 7 + mh;
      float v0, v1, v2;
      if (n == 0) { v0 = sv0; v1 = sv1; v2 = sv2; }
      else {
        int idx = fsi[(n - 1) * PG + gyy * GW + gxx];
        int fi = idx / IDX146; int rem = idx % IDX146;
        int pv = rem / 146, ph = rem % 146;
        int base = (4 + pv + dy) * H160 + (4 + ph + dx);
        v0 = seq[(0 * 7 + fi) * 25600 + base];
        v1 = seq[(1 * 7 + fi) * 25600 + base];
        v2 = seq[(2 * 7 + fi) * 25600 + base];
      }
      X[(size_t)(n * 150 + q * 3 + 0) * P66 + p] = v0;
      X[(size_t)(n * 150 + q * 3 + 1) * P66 + p] = v1;
      X[(size_t)(n * 150 + q * 3 + 2) * P66 + p] = v2;
      float e0 = v0 - sv0, e1 = v1 - sv1, e2 = v2 - sv2;
      w0 += e0 * e0; w1 += e1 * e1; w2 += e2 * e2;
    }
  }
  X[(size_t)(n * 150 + 147) * P66 + p] = w0 / 49.f;
  X[(size_t)(n * 150 + 148) * P66 + p] = w1 / 49.f;
  X[(size_t)(n * 150 + 149) * P66 + p] = w2 / 49.f;
}

// ---------------- k4a: reflect-pad 3 + grouped 7x7 conv (3-in -> 3-out per group) --
__global__ void k4a_vh(const float* __restrict__ in, const float* __restrict__ w,
                       float* __restrict__ out) {
  int g = blockIdx.y;                       // group, o0 = 3g
  int p = blockIdx.x * 256 + threadIdx.x;
  if (p >= P66) return;
  int yo = p / 66, xo = p % 66;
  int o0 = g * 3;
  float a0 = 0.f, a1 = 0.f, a2 = 0.f;
#pragma unroll
  for (int ic = 0; ic < 3; ++ic) {
    const float* ip = in + (size_t)(o0 + ic) * P66;
    for (int ky = 0; ky < 7; ++ky) {
      int iy = yo + ky - 3; iy = iy < 0 ? -iy : (iy > 65 ? 130 - iy : iy);
      for (int kx = 0; kx < 7; ++kx) {
        int ix = xo + kx - 3; ix = ix < 0 ? -ix : (ix > 65 ? 130 - ix : ix);
        float v = ip[iy * 66 + ix];
        int wi = ky * 7 + kx;
        a0 = fmaf(v, w[(o0 + 0) * 147 + ic * 49 + wi], a0);
        a1 = fmaf(v, w[(o0 + 1) * 147 + ic * 49 + wi], a1);
        a2 = fmaf(v, w[(o0 + 2) * 147 + ic * 49 + wi], a2);
      }
    }
  }
  out[(size_t)(o0 + 0) * P66 + p] = a0;
  out[(size_t)(o0 + 1) * P66 + p] = a1;
  out[(size_t)(o0 + 2) * P66 + p] = a2;
}

// ---------------- k4b: 1x1 conv, groups of 150, 6 outputs/thread ----------------
__global__ void k4b_f(const float* __restrict__ in, const float* __restrict__ w,
                      float* __restrict__ out) {
  int ob = blockIdx.y * 6;
  int p = blockIdx.x * 256 + threadIdx.x;
  if (p >= P66) return;
  int gb = (ob / 150) * 150;
  float a0=0.f,a1=0.f,a2=0.f,a3=0.f,a4=0.f,a5=0.f;
  const float* ip = in + (size_t)gb * P66 + p;
  const float* w0 = w + (size_t)ob * 150;
  for (int f = 0; f < 150; ++f) {
    float v = ip[(size_t)f * P66];
    a0 = fmaf(v, w0[f],        a0);
    a1 = fmaf(v, w0[150 + f],  a1);
    a2 = fmaf(v, w0[300 + f],  a2);
    a3 = fmaf(v, w0[450 + f],  a3);
    a4 = fmaf(v, w0[600 + f],  a4);
    a5 = fmaf(v, w0[750 + f],  a5);
  }
  out[(size_t)(ob + 0) * P66 + p] = a0;
  out[(size_t)(ob + 1) * P66 + p] = a1;
  out[(size_t)(ob + 2) * P66 + p] = a2;
  out[(size_t)(ob + 3) * P66 + p] = a3;
  out[(size_t)(ob + 4) * P66 + p] = a4;
  out[(size_t)(ob + 5) * P66 + p] = a5;
}

// ---------------- k4c: neighbor-mix 1x1 (groups of 150 feature channels) ----------
template<int NI, int NO>
__global__ void k4c_n(const float* __restrict__ in, const float* __restrict__ w,
                      const float* __restrict__ bias, float* __restrict__ out, int withbias) {
  int f = blockIdx.y;                       // 0..149
  int p = blockIdx.x * 256 + threadIdx.x;
  if (p >= P66) return;
  float acc[NO];
#pragma unroll
  for (int j = 0; j < NO; ++j) acc[j] = 0.f;
#pragma unroll
  for (int nn = 0; nn < NI; ++nn) {
    float v = in[(size_t)(nn * 150 + f) * P66 + p];
#pragma unroll
    for (int j = 0; j < NO; ++j) acc[j] = fmaf(v, w[(f * NO + j) * NI + nn], acc[j]);
  }
#pragma unroll
  for (int j = 0; j < NO; ++j) {
    float r = acc[j];
    if (withbias) { r += bias[j * 150 + f]; r = r > 0.f ? r : 0.f; }
    out[(size_t)(j * 150 + f) * P66 + p] = r;
  }
}

// ---------------- BN (train-mode batch stats over 66x66) + relu, in place --------
__global__ void k_bn(float* __restrict__ x, const float* __restrict__ g,
                     const float* __restrict__ be) {
  int c = blockIdx.x;
  float* xp = x + (size_t)c * P66;
  __shared__ float red[256];
  int t = threadIdx.x;
  float s = 0.f;
  for (int p = t; p < P66; p += 256) s += xp[p];
  red[t] = s; __syncthreads();
  for (int off = 128; off > 0; off >>= 1) { if (t < off) red[t] += red[t + off]; __syncthreads(); }
  float m = red[0] / (float)P66;
  __syncthreads();
  float s2 = 0.f;
  for (int p = t; p < P66; p += 256) { float dd = xp[p] - m; s2 += dd * dd; }
  red[t] = s2; __syncthreads();
  for (int off = 128; off > 0; off >>= 1) { if (t < off) red[t] += red[t + off]; __syncthreads(); }
  float var = red[0] / (float)P66;
  float sc = g[c] / sqrtf(var + 1e-5f);
  float sh = be[c] - m * sc;
  for (int p = t; p < P66; p += 256) { float r = fmaf(xp[p], sc, sh); xp[p] = r > 0.f ? r : 0.f; }
}

// ---------------- final: w_f4 (150->3) + b4, out = valid - y ----------------------
__global__ void k_final(const float* __restrict__ in, const float* __restrict__ wf,
                        const float* __restrict__ b4, const float* __restrict__ seq,
                        float* __restrict__ out) {
  int p = blockIdx.x * 256 + threadIdx.x;
  if (p >= P66) return;
  int yo = p / 66, xo = p % 66;
  float a0 = 0.f, a1 = 0.f, a2 = 0.f;
  for (int f = 0; f < 150; ++f) {
    float v = in[(size_t)f * P66 + p];
    a0 = fmaf(v, wf[f],       a0);
    a1 = fmaf(v, wf[150 + f], a1);
    a2 = fmaf(v, wf[300 + f], a2);
  }
  float y0 = a0 + b4[0], y1 = a1 + b4[1], y2 = a2 + b4[2];
  int vo = (47 + yo) * H160 + (47 + xo);
  out[0 * P66 + p] = seq[(0 * 7 + 3) * 25600 + vo] - y0;
  out[1 * P66 + p] = seq[(1 * 7 + 3) * 25600 + vo] - y1;
  out[2 * P66 + p] = seq[(2 * 7 + 3) * 25600 + vo] - y2;
}

extern "C" void kernel_launch(void* const* d_in, const int* in_sizes, int n_in,
                              void* d_out, int out_size, void* d_ws, size_t ws_size,
                              hipStream_t stream) {
  // setup_inputs() dict order:
  const float* seq   = (const float*)d_in[0];   // (1,3,7,160,160)
  // d_in[1] = gpu_usage (unused)
  const float* w_vh0 = (const float*)d_in[2];
  const float* w_f0  = (const float*)d_in[3];
  const float* w_n0  = (const float*)d_in[4];
  const float* w_vh1 = (const float*)d_in[5];
  const float* w_f1  = (const float*)d_in[6];
  const float* w_n1  = (const float*)d_in[7];
  const float* w_vh2 = (const float*)d_in[8];
  const float* w_f2  = (const float*)d_in[9];
  const float* w_n2  = (const float*)d_in[10];
  const float* w_vh3 = (const float*)d_in[11];
  const float* w_f3  = (const float*)d_in[12];
  const float* w_n3  = (const float*)d_in[13];
  const float* b0    = (const float*)d_in[14];
  const float* g1    = (const float*)d_in[15];
  const float* be1   = (const float*)d_in[16];
  const float* g2    = (const float*)d_in[17];
  const float* be2   = (const float*)d_in[18];
  const float* g3    = (const float*)d_in[19];
  const float* be3   = (const float*)d_in[20];
  const float* w_vh4 = (const float*)d_in[21];
  const float* w_f4  = (const float*)d_in[22];
  const float* b4    = (const float*)d_in[23];
  float* outp = (float*)d_out;

  // workspace layout (floats): ~93 MB total
  float* fws  = (float*)d_ws;
  float* seqT = fws;                              // 537600
  float* sd   = seqT + 537600;                    // 21*14*5184 = 1524096
  int*   si   = (int*)(sd + 1524096);             // 1524096
  float* X    = (float*)(si + 1524096);           // 9801000 (2250*4356)
  float* A    = X + 9801000;                      // 9801000
  int*   fsi  = (int*)(A + 9801000);              // 72576
  float* wsD  = X;                                // alias: 2625*5184 = 13.6M fits in X+A

  k0_transpose<<<dim3(160, 21), 160, 0, stream>>>(seq, seqT);
  k_init<<<(1524096 + 255) / 256, 256, 0, stream>>>(sd, 1524096);
  for (int c = 0; c < NCHUNK; ++c) {
    k1_dist<<<CHUNK, 128, 0, stream>>>(seqT, wsD, c * CHUNK);
    k2_topk<<<dim3(81, NBANK), 64, 0, stream>>>(wsD, sd, si, c * CHUNK);
  }
  k_merge<<<81, 64, 0, stream>>>(sd, si, fsi);
  k3_layers<<<dim3(18, 15), 256, 0, stream>>>(seq, fsi, X);

  // L0: X -> A -> X -> A(1200) [+b0, relu]
  k4a_vh<<<dim3(18, 750), 256, 0, stream>>>(X, w_vh0, A);
  k4b_f <<<dim3(18, 375), 256, 0, stream>>>(A, w_f0, X);
  k4c_n<15, 8><<<dim3(18, 150), 256, 0, stream>>>(X, w_n0, b0, A, 1);
  // L1: A -> X -> A -> X(600), BN(g1,be1)+relu
  k4a_vh<<<dim3(18, 400), 256, 0, stream>>>(A, w_vh1, X);
  k4b_f <<<dim3(18, 200), 256, 0, stream>>>(X, w_f1, A);
  k4c_n<8, 4><<<dim3(18, 150), 256, 0, stream>>>(A, w_n1, nullptr, X, 0);
  k_bn<<<600, 256, 0, stream>>>(X, g1, be1);
  // L2: X -> A -> X -> A(300), BN(g2,be2)+relu
  k4a_vh<<<dim3(18, 200), 256, 0, stream>>>(X, w_vh2, A);
  k4b_f <<<dim3(18, 100), 256, 0, stream>>>(A, w_f2, X);
  k4c_n<4, 2><<<dim3(18, 150), 256, 0, stream>>>(X, w_n2, nullptr, A, 0);
  k_bn<<<300, 256, 0, stream>>>(A, g2, be2);
  // L3: A -> X -> A -> X(150), BN(g3,be3)+relu
  k4a_vh<<<dim3(18, 100), 256, 0, stream>>>(A, w_vh3, X);
  k4b_f <<<dim3(18, 50), 256, 0, stream>>>(X, w_f3, A);
  k4c_n<2, 1><<<dim3(18, 150), 256, 0, stream>>>(A, w_n3, nullptr, X, 0);
  k_bn<<<150, 256, 0, stream>>>(X, g3, be3);
  // L4: X -> A(150), then w_f4 + b4, out = valid - y
  k4a_vh<<<dim3(18, 50), 256, 0, stream>>>(X, w_vh4, A);
  k_final<<<18, 256, 0, stream>>>(A, w_f4, b4, seq, outp);
}

// Round 2
// 2652.519 us; speedup vs baseline: 1.4375x; 1.4375x over previous
//
#include <hip/hip_runtime.h>
#include <cstdint>
#include <cstddef>

// ---------------- constants ----------------
#define H160   160
#define CHS    179200      // 7*160*160 (channel stride in seq / seqT)
#define HD     86          // h-74
#define GW     72          // grid width (72x72 points)
#define PG     5184        // 72*72
#define P66    4356        // 66*66
#define IDX146 21316       // 146*146
#define NVNH   5625        // 75*75
#define SELF_CAND 19687    // 3*5625 + 37*75 + 37
#define CHUNK  2625        // candidates per chunk (39375 = 15*2625)
#define NCHUNK 15
#define NBANK  21          // 2625 = 21*125
#define BANKLEN 125
#define INFF __int_as_float(0x7f800000)

// ---------------- k0: transpose seq -> seqT[pl][x][y] ----------------
__global__ void k0_transpose(const float* __restrict__ seq, float* __restrict__ seqT) {
  int pl = blockIdx.y;           // 0..20  (c*7+t)
  int x  = blockIdx.x;           // 0..159
  int y  = threadIdx.x;          // 0..159
  seqT[(pl * H160 + x) * H160 + y] = seq[(pl * H160 + y) * H160 + x];
}

// ---------------- init distances to +inf ----------------
__global__ void k_init(float* __restrict__ sd, int n) {
  int i = blockIdx.x * 256 + threadIdx.x;
  if (i < n) sd[i] = INFF;
}

// ---------------- k1: per-candidate boxed distance field (bitwise-replicates
// numpy: d = mean_c((win-seq_n)^2); box15 via sequential fp32 cumsum diffs).
// Round 2: col[] LDS removed (16-deep register ring, same fp32 op order);
// cs padded to stride 87 (odd -> free 2-way LDS aliasing). 29.9 KB LDS ->
// 5 blocks/CU vs 2. ----
__global__ __launch_bounds__(128) void k1_dist(const float* __restrict__ seqT,
                                               float* __restrict__ wsD, int chunkBase) {
  __shared__ float cs[HD][87];   // row prefix sums, padded stride
  int cand = chunkBase + (int)blockIdx.x;
  int ts = cand / NVNH;
  int rr = cand % NVNH;
  int vs = rr / 75;
  int hv = rr % 75;
  int t = threadIdx.x;
  if (t < HD) {
    int y = t;
    const float* pa = seqT + (ts * H160 + hv) * H160 + (vs + y);      // ch0, +x*160
    const float* pb = seqT + (3  * H160 + 37) * H160 + (37 + y);      // frame3 target
    float c0 = 0.f;
    for (int x = 0; x < HD; ++x) {
      int o = x * H160;
      float d0 = __fsub_rn(pa[o],            pb[o]);
      float d1 = __fsub_rn(pa[o + CHS],      pb[o + CHS]);
      float d2 = __fsub_rn(pa[o + 2 * CHS],  pb[o + 2 * CHS]);
      float s  = __fadd_rn(__fadd_rn(__fmul_rn(d0, d0), __fmul_rn(d1, d1)), __fmul_rn(d2, d2));
      float dd = __fdiv_rn(s, 3.0f);
      c0 = __fadd_rn(c0, dd);
      cs[y][x] = c0;
    }
  }
  __syncthreads();
  if (t < GW) {
    int jm = (t == 0) ? 0 : (t - 1);     // safe index; value unused when t==0
    float cc = 0.f;
    float ring[16];
    float* D = wsD + (size_t)blockIdx.x * PG;
#pragma unroll
    for (int r = 0; r < HD; ++r) {
      float v = (t == 0) ? cs[r][14] : __fsub_rn(cs[r][t + 14], cs[r][jm]);
      cc = __fadd_rn(cc, v);
      ring[r & 15] = cc;
      if (r >= 14) {
        int gy = r - 14;
        float out = (gy == 0) ? cc : __fsub_rn(cc, ring[(gy - 1) & 15]);
        D[gy * GW + t] = out;
      }
    }
  }
}

// ---------------- k2: banked top-14 update (strict-less insert == stable top_k).
// Round 2: candidate distances loaded 5 at a time (independent addresses) so
// the 125-deep serial loop exposes ~5x less memory latency. ----
__global__ __launch_bounds__(64) void k2_topk(const float* __restrict__ wsD,
                                              float* __restrict__ sd, int* __restrict__ si,
                                              int chunkBase) {
  int pid = blockIdx.x * 64 + threadIdx.x;      // 5184 = 81*64
  int s = blockIdx.y;                           // bank
  float d[14]; int id[14];
#pragma unroll
  for (int k = 0; k < 14; ++k) { d[k] = sd[(s * 14 + k) * PG + pid]; id[k] = si[(s * 14 + k) * PG + pid]; }
  int gy = pid / GW, gx = pid % GW;
  const float* Dp = wsD + (size_t)(s * BANKLEN) * PG + pid;
  for (int i = 0; i < BANKLEN; i += 5) {
    float dist[5];
#pragma unroll
    for (int u = 0; u < 5; ++u) dist[u] = Dp[(size_t)(i + u) * PG];
#pragma unroll
    for (int u = 0; u < 5; ++u) {
      int c = s * BANKLEN + i + u;
      int cand = chunkBase + c;
      if (cand == SELF_CAND) continue;
      if (dist[u] < d[13]) {
        int ts = cand / NVNH;
        int rr = cand % NVNH;
        int vs = rr / 75, hvv = rr % 75;
        int idx = ts * IDX146 + (gy + vs) * 146 + (gx + hvv);
#pragma unroll
        for (int j = 13; j >= 1; --j) {
          bool shift = dist[u] < d[j - 1];
          bool here  = dist[u] < d[j];
          float nv = shift ? d[j - 1]  : (here ? dist[u] : d[j]);
          int   ni = shift ? id[j - 1] : (here ? idx     : id[j]);
          d[j] = nv; id[j] = ni;
        }
        if (dist[u] < d[0]) { id[0] = idx; d[0] = dist[u]; }
      }
    }
  }
#pragma unroll
  for (int k = 0; k < 14; ++k) { sd[(s * 14 + k) * PG + pid] = d[k]; si[(s * 14 + k) * PG + pid] = id[k]; }
}

// ---------------- merge 21 sorted banks -> final 14 (tie-break by candidate time) --
__global__ __launch_bounds__(64) void k_merge(const float* __restrict__ sd,
                                              const int* __restrict__ si,
                                              int* __restrict__ fsi) {
  int pid = blockIdx.x * 64 + threadIdx.x;
  int gy = pid / GW, gx = pid % GW;
  int cur[NBANK];
  for (int s = 0; s < NBANK; ++s) cur[s] = 0;
  for (int o = 0; o < 14; ++o) {
    float bd = INFF; int bt = 0x7fffffff; int bs = 0; int bi = 0;
    for (int s = 0; s < NBANK; ++s) {
      if (cur[s] >= 14) continue;
      float dd = sd[(s * 14 + cur[s]) * PG + pid];
      int ii  = si[(s * 14 + cur[s]) * PG + pid];
      int ts = ii / IDX146; int rem = ii % IDX146;
      int pv = rem / 146, ph = rem % 146;
      int tt = (ts * 75 + (pv - gy)) * 75 + (ph - gx);
      if (dd < bd || (dd == bd && tt < bt)) { bd = dd; bt = tt; bs = s; bi = ii; }
    }
    fsi[o * PG + pid] = bi;
    cur[bs]++;
  }
}

// ---------------- k3: build x_f = [layers(147), wts(3)] per neighbor slot ----------
__global__ void k3_layers(const float* __restrict__ seq, const int* __restrict__ fsi,
                          float* __restrict__ X) {
  int n = blockIdx.y;                       // 0..14
  int p = blockIdx.x * 256 + threadIdx.x;
  if (p >= P66) return;
  int yo = p / 66, xo = p % 66;
  int y = yo + 6, x = xo + 6;
  float sv0 = seq[(0 * 7 + 3) * 25600 + (41 + y) * H160 + (41 + x)];
  float sv1 = seq[(1 * 7 + 3) * 25600 + (41 + y) * H160 + (41 + x)];
  float sv2 = seq[(2 * 7 + 3) * 25600 + (41 + y) * H160 + (41 + x)];
  float w0 = 0.f, w1 = 0.f, w2 = 0.f;
  for (int mv = 0; mv < 7; ++mv) {
    int dy = (y - mv) % 7; int gyy = y - dy;
    for (int mh = 0; mh < 7; ++mh) {
      int dx = (x - mh) % 7; int gxx = x - dx;
      int q = mv * 7 + mh;
      float v0, v1, v2;
      if (n == 0) { v0 = sv0; v1 = sv1; v2 = sv2; }
      else {
        int idx = fsi[(n - 1) * PG + gyy * GW + gxx];
        int fi = idx / IDX146; int rem = idx % IDX146;
        int pv = rem / 146, ph = rem % 146;
        int base = (4 + pv + dy) * H160 + (4 + ph + dx);
        v0 = seq[(0 * 7 + fi) * 25600 + base];
        v1 = seq[(1 * 7 + fi) * 25600 + base];
        v2 = seq[(2 * 7 + fi) * 25600 + base];
      }
      X[(size_t)(n * 150 + q * 3 + 0) * P66 + p] = v0;
      X[(size_t)(n * 150 + q * 3 + 1) * P66 + p] = v1;
      X[(size_t)(n * 150 + q * 3 + 2) * P66 + p] = v2;
      float e0 = v0 - sv0, e1 = v1 - sv1, e2 = v2 - sv2;
      w0 += e0 * e0; w1 += e1 * e1; w2 += e2 * e2;
    }
  }
  X[(size_t)(n * 150 + 147) * P66 + p] = w0 / 49.f;
  X[(size_t)(n * 150 + 148) * P66 + p] = w1 / 49.f;
  X[(size_t)(n * 150 + 149) * P66 + p] = w2 / 49.f;
}

// ---------------- k4a: reflect-pad 3 + grouped 7x7 conv (3-in -> 3-out per group) --
__global__ void k4a_vh(const float* __restrict__ in, const float* __restrict__ w,
                       float* __restrict__ out) {
  int g = blockIdx.y;                       // group, o0 = 3g
  int p = blockIdx.x * 256 + threadIdx.x;
  if (p >= P66) return;
  int yo = p / 66, xo = p % 66;
  int o0 = g * 3;
  float a0 = 0.f, a1 = 0.f, a2 = 0.f;
#pragma unroll
  for (int ic = 0; ic < 3; ++ic) {
    const float* ip = in + (size_t)(o0 + ic) * P66;
    for (int ky = 0; ky < 7; ++ky) {
      int iy = yo + ky - 3; iy = iy < 0 ? -iy : (iy > 65 ? 130 - iy : iy);
      for (int kx = 0; kx < 7; ++kx) {
        int ix = xo + kx - 3; ix = ix < 0 ? -ix : (ix > 65 ? 130 - ix : ix);
        float v = ip[iy * 66 + ix];
        int wi = ky * 7 + kx;
        a0 = fmaf(v, w[(o0 + 0) * 147 + ic * 49 + wi], a0);
        a1 = fmaf(v, w[(o0 + 1) * 147 + ic * 49 + wi], a1);
        a2 = fmaf(v, w[(o0 + 2) * 147 + ic * 49 + wi], a2);
      }
    }
  }
  out[(size_t)(o0 + 0) * P66 + p] = a0;
  out[(size_t)(o0 + 1) * P66 + p] = a1;
  out[(size_t)(o0 + 2) * P66 + p] = a2;
}

// ---------------- k4b: 1x1 conv, groups of 150, 6 outputs/thread ----------------
__global__ void k4b_f(const float* __restrict__ in, const float* __restrict__ w,
                      float* __restrict__ out) {
  int ob = blockIdx.y * 6;
  int p = blockIdx.x * 256 + threadIdx.x;
  if (p >= P66) return;
  int gb = (ob / 150) * 150;
  float a0=0.f,a1=0.f,a2=0.f,a3=0.f,a4=0.f,a5=0.f;
  const float* ip = in + (size_t)gb * P66 + p;
  const float* w0 = w + (size_t)ob * 150;
  for (int f = 0; f < 150; ++f) {
    float v = ip[(size_t)f * P66];
    a0 = fmaf(v, w0[f],        a0);
    a1 = fmaf(v, w0[150 + f],  a1);
    a2 = fmaf(v, w0[300 + f],  a2);
    a3 = fmaf(v, w0[450 + f],  a3);
    a4 = fmaf(v, w0[600 + f],  a4);
    a5 = fmaf(v, w0[750 + f],  a5);
  }
  out[(size_t)(ob + 0) * P66 + p] = a0;
  out[(size_t)(ob + 1) * P66 + p] = a1;
  out[(size_t)(ob + 2) * P66 + p] = a2;
  out[(size_t)(ob + 3) * P66 + p] = a3;
  out[(size_t)(ob + 4) * P66 + p] = a4;
  out[(size_t)(ob + 5) * P66 + p] = a5;
}

// ---------------- k4c: neighbor-mix 1x1 (groups of 150 feature channels) ----------
template<int NI, int NO>
__global__ void k4c_n(const float* __restrict__ in, const float* __restrict__ w,
                      const float* __restrict__ bias, float* __restrict__ out, int withbias) {
  int f = blockIdx.y;                       // 0..149
  int p = blockIdx.x * 256 + threadIdx.x;
  if (p >= P66) return;
  float acc[NO];
#pragma unroll
  for (int j = 0; j < NO; ++j) acc[j] = 0.f;
#pragma unroll
  for (int nn = 0; nn < NI; ++nn) {
    float v = in[(size_t)(nn * 150 + f) * P66 + p];
#pragma unroll
    for (int j = 0; j < NO; ++j) acc[j] = fmaf(v, w[(f * NO + j) * NI + nn], acc[j]);
  }
#pragma unroll
  for (int j = 0; j < NO; ++j) {
    float r = acc[j];
    if (withbias) { r += bias[j * 150 + f]; r = r > 0.f ? r : 0.f; }
    out[(size_t)(j * 150 + f) * P66 + p] = r;
  }
}

// ---------------- BN (train-mode batch stats over 66x66) + relu, in place --------
__global__ void k_bn(float* __restrict__ x, const float* __restrict__ g,
                     const float* __restrict__ be) {
  int c = blockIdx.x;
  float* xp = x + (size_t)c * P66;
  __shared__ float red[256];
  int t = threadIdx.x;
  float s = 0.f;
  for (int p = t; p < P66; p += 256) s += xp[p];
  red[t] = s; __syncthreads();
  for (int off = 128; off > 0; off >>= 1) { if (t < off) red[t] += red[t + off]; __syncthreads(); }
  float m = red[0] / (float)P66;
  __syncthreads();
  float s2 = 0.f;
  for (int p = t; p < P66; p += 256) { float dd = xp[p] - m; s2 += dd * dd; }
  red[t] = s2; __syncthreads();
  for (int off = 128; off > 0; off >>= 1) { if (t < off) red[t] += red[t + off]; __syncthreads(); }
  float var = red[0] / (float)P66;
  float sc = g[c] / sqrtf(var + 1e-5f);
  float sh = be[c] - m * sc;
  for (int p = t; p < P66; p += 256) { float r = fmaf(xp[p], sc, sh); xp[p] = r > 0.f ? r : 0.f; }
}

// ---------------- final: w_f4 (150->3) + b4, out = valid - y ----------------------
__global__ void k_final(const float* __restrict__ in, const float* __restrict__ wf,
                        const float* __restrict__ b4, const float* __restrict__ seq,
                        float* __restrict__ out) {
  int p = blockIdx.x * 256 + threadIdx.x;
  if (p >= P66) return;
  int yo = p / 66, xo = p % 66;
  float a0 = 0.f, a1 = 0.f, a2 = 0.f;
  for (int f = 0; f < 150; ++f) {
    float v = in[(size_t)f * P66 + p];
    a0 = fmaf(v, wf[f],       a0);
    a1 = fmaf(v, wf[150 + f], a1);
    a2 = fmaf(v, wf[300 + f], a2);
  }
  float y0 = a0 + b4[0], y1 = a1 + b4[1], y2 = a2 + b4[2];
  int vo = (47 + yo) * H160 + (47 + xo);
  out[0 * P66 + p] = seq[(0 * 7 + 3) * 25600 + vo] - y0;
  out[1 * P66 + p] = seq[(1 * 7 + 3) * 25600 + vo] - y1;
  out[2 * P66 + p] = seq[(2 * 7 + 3) * 25600 + vo] - y2;
}

extern "C" void kernel_launch(void* const* d_in, const int* in_sizes, int n_in,
                              void* d_out, int out_size, void* d_ws, size_t ws_size,
                              hipStream_t stream) {
  // setup_inputs() dict order:
  const float* seq   = (const float*)d_in[0];   // (1,3,7,160,160)
  // d_in[1] = gpu_usage (unused)
  const float* w_vh0 = (const float*)d_in[2];
  const float* w_f0  = (const float*)d_in[3];
  const float* w_n0  = (const float*)d_in[4];
  const float* w_vh1 = (const float*)d_in[5];
  const float* w_f1  = (const float*)d_in[6];
  const float* w_n1  = (const float*)d_in[7];
  const float* w_vh2 = (const float*)d_in[8];
  const float* w_f2  = (const float*)d_in[9];
  const float* w_n2  = (const float*)d_in[10];
  const float* w_vh3 = (const float*)d_in[11];
  const float* w_f3  = (const float*)d_in[12];
  const float* w_n3  = (const float*)d_in[13];
  const float* b0    = (const float*)d_in[14];
  const float* g1    = (const float*)d_in[15];
  const float* be1   = (const float*)d_in[16];
  const float* g2    = (const float*)d_in[17];
  const float* be2   = (const float*)d_in[18];
  const float* g3    = (const float*)d_in[19];
  const float* be3   = (const float*)d_in[20];
  const float* w_vh4 = (const float*)d_in[21];
  const float* w_f4  = (const float*)d_in[22];
  const float* b4    = (const float*)d_in[23];
  float* outp = (float*)d_out;

  // workspace layout (floats): ~93 MB total
  float* fws  = (float*)d_ws;
  float* seqT = fws;                              // 537600
  float* sd   = seqT + 537600;                    // 21*14*5184 = 1524096
  int*   si   = (int*)(sd + 1524096);             // 1524096
  float* X    = (float*)(si + 1524096);           // 9801000 (2250*4356)
  float* A    = X + 9801000;                      // 9801000
  int*   fsi  = (int*)(A + 9801000);              // 72576
  float* wsD  = X;                                // alias: 2625*5184 = 13.6M fits in X+A

  k0_transpose<<<dim3(160, 21), 160, 0, stream>>>(seq, seqT);
  k_init<<<(1524096 + 255) / 256, 256, 0, stream>>>(sd, 1524096);
  for (int c = 0; c < NCHUNK; ++c) {
    k1_dist<<<CHUNK, 128, 0, stream>>>(seqT, wsD, c * CHUNK);
    k2_topk<<<dim3(81, NBANK), 64, 0, stream>>>(wsD, sd, si, c * CHUNK);
  }
  k_merge<<<81, 64, 0, stream>>>(sd, si, fsi);
  k3_layers<<<dim3(18, 15), 256, 0, stream>>>(seq, fsi, X);

  // L0: X -> A -> X -> A(1200) [+b0, relu]
  k4a_vh<<<dim3(18, 750), 256, 0, stream>>>(X, w_vh0, A);
  k4b_f <<<dim3(18, 375), 256, 0, stream>>>(A, w_f0, X);
  k4c_n<15, 8><<<dim3(18, 150), 256, 0, stream>>>(X, w_n0, b0, A, 1);
  // L1: A -> X -> A -> X(600), BN(g1,be1)+relu
  k4a_vh<<<dim3(18, 400), 256, 0, stream>>>(A, w_vh1, X);
  k4b_f <<<dim3(18, 200), 256, 0, stream>>>(X, w_f1, A);
  k4c_n<8, 4><<<dim3(18, 150), 256, 0, stream>>>(A, w_n1, nullptr, X, 0);
  k_bn<<<600, 256, 0, stream>>>(X, g1, be1);
  // L2: X -> A -> X -> A(300), BN(g2,be2)+relu
  k4a_vh<<<dim3(18, 200), 256, 0, stream>>>(X, w_vh2, A);
  k4b_f <<<dim3(18, 100), 256, 0, stream>>>(A, w_f2, X);
  k4c_n<4, 2><<<dim3(18, 150), 256, 0, stream>>>(X, w_n2, nullptr, A, 0);
  k_bn<<<300, 256, 0, stream>>>(A, g2, be2);
  // L3: A -> X -> A -> X(150), BN(g3,be3)+relu
  k4a_vh<<<dim3(18, 100), 256, 0, stream>>>(A, w_vh3, X);
  k4b_f <<<dim3(18, 50), 256, 0, stream>>>(X, w_f3, A);
  k4c_n<2, 1><<<dim3(18, 150), 256, 0, stream>>>(A, w_n3, nullptr, X, 0);
  k_bn<<<150, 256, 0, stream>>>(X, g3, be3);
  // L4: X -> A(150), then w_f4 + b4, out = valid - y
  k4a_vh<<<dim3(18, 50), 256, 0, stream>>>(X, w_vh4, A);
  k_final<<<18, 256, 0, stream>>>(A, w_f4, b4, seq, outp);
}

// Round 3
// 2425.388 us; speedup vs baseline: 1.5722x; 1.0936x over previous
//
#include <hip/hip_runtime.h>
#include <cstdint>
#include <cstddef>

// ---------------- constants ----------------
#define H160   160
#define CHS    179200      // 7*160*160 (channel stride in seq / seqT)
#define HD     86          // h-74
#define GW     72          // grid width (72x72 points)
#define PG     5184        // 72*72
#define P66    4356        // 66*66
#define IDX146 21316       // 146*146
#define NVNH   5625        // 75*75
#define SELF_CAND 19687    // 3*5625 + 37*75 + 37
#define CHUNK  2625        // candidates per chunk (39375 = 15*2625)
#define NCHUNK 15
#define NSLOT  21          // persistent top-14 slots (banks), 125 cands each per chunk
#define SLOTLEN 125
typedef unsigned long long u64;

// ---------------- k0: transpose seq -> seqT[pl][x][y] ----------------
__global__ void k0_transpose(const float* __restrict__ seq, float* __restrict__ seqT) {
  int pl = blockIdx.y;           // 0..20  (c*7+t)
  int x  = blockIdx.x;           // 0..159
  int y  = threadIdx.x;          // 0..159
  seqT[(pl * H160 + x) * H160 + y] = seq[(pl * H160 + y) * H160 + x];
}

// ---------------- init state keys to max ----------------
__global__ void k_init(u64* __restrict__ sk, int n) {
  int i = blockIdx.x * 256 + threadIdx.x;
  if (i < n) sk[i] = ~0ULL;
}

// ---------------- k1: per-candidate boxed distance field (bitwise-replicates
// numpy: d = mean_c((win-seq_n)^2); box15 via sequential fp32 cumsum diffs).
// Round 3: exact div-by-3 via Markstein 2-fma sequence (correctly rounded for
// normal inputs; removes v_div mode-switch stalls); 2 candidates per block
// (1313 blocks = ~5/CU, no second occupancy round); x-loop unrolled. ----
__global__ __launch_bounds__(128) void k1_dist(const float* __restrict__ seqT,
                                               float* __restrict__ wsD, int chunkBase) {
  __shared__ float cs[HD][87];   // row prefix sums, padded stride
  const float R3 = 0.33333334f;  // RN(1/3) = 0x3EAAAAAB
  int t = threadIdx.x;
  for (int half = 0; half < 2; ++half) {
    int cidx = (int)blockIdx.x * 2 + half;
    if (cidx < CHUNK) {                       // block-uniform guard
      int cand = chunkBase + cidx;
      int ts = cand / NVNH;
      int rr = cand % NVNH;
      int vs = rr / 75;
      int hv = rr % 75;
      if (half) __syncthreads();              // protect cs reuse across halves
      if (t < HD) {
        int y = t;
        const float* pa = seqT + (ts * H160 + hv) * H160 + (vs + y);
        const float* pb = seqT + (3  * H160 + 37) * H160 + (37 + y);
        float c0 = 0.f;
#pragma unroll 2
        for (int x = 0; x < HD; ++x) {
          int o = x * H160;
          float d0 = __fsub_rn(pa[o],            pb[o]);
          float d1 = __fsub_rn(pa[o + CHS],      pb[o + CHS]);
          float d2 = __fsub_rn(pa[o + 2 * CHS],  pb[o + 2 * CHS]);
          float s  = __fadd_rn(__fadd_rn(__fmul_rn(d0, d0), __fmul_rn(d1, d1)), __fmul_rn(d2, d2));
          // dd = RN(s/3) via Markstein: q0=RN(s*r3); e=fma(-3,q0,s); dd=RN(q0+e*r3)
          float q0 = __fmul_rn(s, R3);
          float e  = __builtin_fmaf(-3.0f, q0, s);
          float dd = __builtin_fmaf(e, R3, q0);
          c0 = __fadd_rn(c0, dd);
          cs[y][x] = c0;
        }
      }
      __syncthreads();
      if (t < GW) {
        int jm = (t == 0) ? 0 : (t - 1);
        float cc = 0.f;
        float ring[16];
        float* D = wsD + (size_t)cidx * PG;
#pragma unroll
        for (int r = 0; r < HD; ++r) {
          float v = (t == 0) ? cs[r][14] : __fsub_rn(cs[r][t + 14], cs[r][jm]);
          cc = __fadd_rn(cc, v);
          ring[r & 15] = cc;
          if (r >= 14) {
            int gy = r - 14;
            float out = (gy == 0) ? cc : __fsub_rn(cc, ring[(gy - 1) & 15]);
            D[gy * GW + t] = out;
          }
        }
      }
    }
  }
}

// ---------------- k2: banked top-14 via u64 sort keys.
// key = (float_bits(d)<<32)|cand : since d>=0, unsigned-u64 order == lex (d,cand)
// order, which is exactly the reference's stable-top_k semantics. 4 waves split
// each bank's 125 candidates (burst-loaded, one latency exposure), then wave0
// 5-way-merges {4 wave lists + prior state} in LDS and writes state back. ----
__global__ __launch_bounds__(256) void k2_topk(const float* __restrict__ wsD,
                                               u64* __restrict__ sk, int chunkBase) {
  __shared__ u64 lk[5][14][64];
  int tid = threadIdx.x;
  int w = tid >> 6, lane = tid & 63;
  int s = blockIdx.y;
  int pid = (int)blockIdx.x * 64 + lane;
  // wave0 gets the short range (it also loads state + merges)
  int st  = (w == 0) ? 96 : (w - 1) * 32;     // 96 | 0 | 32 | 64
  int cnt = (w == 0) ? 29 : 32;

  // state prefetch (wave0) -> LDS slot 4
  if (w == 0) {
#pragma unroll
    for (int k = 0; k < 14; ++k)
      lk[4][k][lane] = sk[(size_t)(s * 14 + k) * PG + pid];
  }
  // burst-load this wave's candidate distances (independent -> pipelined)
  float dv[32];
  const float* Dp = wsD + (size_t)(s * SLOTLEN + st) * PG + pid;
#pragma unroll
  for (int u = 0; u < 32; ++u)
    if (u < cnt) dv[u] = Dp[(size_t)u * PG];

  // scan: maintain 14 smallest keys
  u64 key[14];
#pragma unroll
  for (int k = 0; k < 14; ++k) key[k] = ~0ULL;
  int cand0 = chunkBase + s * SLOTLEN + st;
#pragma unroll
  for (int u = 0; u < 32; ++u) {
    if (u < cnt) {
      int cand = cand0 + u;                   // wave-uniform
      if (cand != SELF_CAND) {
        u64 nk = ((u64)__float_as_uint(dv[u]) << 32) | (unsigned)cand;
        if (nk < key[13]) {
#pragma unroll
          for (int j = 13; j >= 1; --j)
            key[j] = (nk < key[j - 1]) ? key[j - 1] : ((nk < key[j]) ? nk : key[j]);
          if (nk < key[0]) key[0] = nk;
        }
      }
    }
  }
#pragma unroll
  for (int k = 0; k < 14; ++k) lk[w][k][lane] = key[k];
  __syncthreads();
  if (w != 0) return;

  // exact 5-way merge of sorted lists; ties impossible (distinct cand low bits)
  int h0 = 0, h1 = 0, h2 = 0, h3 = 0, h4 = 0;
  u64 a0 = lk[0][0][lane], a1 = lk[1][0][lane], a2 = lk[2][0][lane],
      a3 = lk[3][0][lane], a4 = lk[4][0][lane];
#pragma unroll
  for (int o = 0; o < 14; ++o) {
    u64 b01 = a0 < a1 ? a0 : a1; int j01 = a0 < a1 ? 0 : 1;
    u64 b23 = a2 < a3 ? a2 : a3; int j23 = a2 < a3 ? 2 : 3;
    u64 b03 = b01 < b23 ? b01 : b23; int j03 = b01 < b23 ? j01 : j23;
    u64 best = b03 < a4 ? b03 : a4; int bj = b03 < a4 ? j03 : 4;
    sk[(size_t)(s * 14 + o) * PG + pid] = best;
    h0 += (bj == 0); h1 += (bj == 1); h2 += (bj == 2); h3 += (bj == 3); h4 += (bj == 4);
    int c0 = h0 < 14 ? h0 : 13, c1 = h1 < 14 ? h1 : 13, c2 = h2 < 14 ? h2 : 13,
        c3 = h3 < 14 ? h3 : 13, c4 = h4 < 14 ? h4 : 13;
    a0 = lk[0][c0][lane]; if (h0 >= 14) a0 = ~0ULL;
    a1 = lk[1][c1][lane]; if (h1 >= 14) a1 = ~0ULL;
    a2 = lk[2][c2][lane]; if (h2 >= 14) a2 = ~0ULL;
    a3 = lk[3][c3][lane]; if (h3 >= 14) a3 = ~0ULL;
    a4 = lk[4][c4][lane]; if (h4 >= 14) a4 = ~0ULL;
  }
}

// ---------------- merge 21 slot lists -> final 14 indices ----------------
__global__ __launch_bounds__(64) void k_merge(const u64* __restrict__ sk,
                                              int* __restrict__ fsi) {
  int pid = (int)blockIdx.x * 64 + threadIdx.x;
  int gy = pid / GW, gx = pid % GW;
  int cur[NSLOT];
#pragma unroll
  for (int s = 0; s < NSLOT; ++s) cur[s] = 0;
  for (int o = 0; o < 14; ++o) {
    u64 bk = ~0ULL; int bs = 0;
#pragma unroll
    for (int s = 0; s < NSLOT; ++s) {
      int cc = cur[s] < 14 ? cur[s] : 13;
      u64 kk = sk[(size_t)(s * 14 + cc) * PG + pid];
      if (cur[s] >= 14) kk = ~0ULL;
      if (kk < bk) { bk = kk; bs = s; }
    }
#pragma unroll
    for (int s = 0; s < NSLOT; ++s) cur[s] += (bs == s) ? 1 : 0;
    int cand = (int)(unsigned)(bk & 0xffffffffULL);
    int ts = cand / NVNH;
    int rr = cand % NVNH;
    int vs = rr / 75, hv = rr % 75;
    fsi[o * PG + pid] = ts * IDX146 + (gy + vs) * 146 + (gx + hv);
  }
}

// ---------------- k3: build x_f = [layers(147), wts(3)] per neighbor slot ----------
__global__ void k3_layers(const float* __restrict__ seq, const int* __restrict__ fsi,
                          float* __restrict__ X) {
  int n = blockIdx.y;                       // 0..14
  int p = (int)blockIdx.x * 256 + threadIdx.x;
  if (p >= P66) return;
  int yo = p / 66, xo = p % 66;
  int y = yo + 6, x = xo + 6;
  float sv0 = seq[(0 * 7 + 3) * 25600 + (41 + y) * H160 + (41 + x)];
  float sv1 = seq[(1 * 7 + 3) * 25600 + (41 + y) * H160 + (41 + x)];
  float sv2 = seq[(2 * 7 + 3) * 25600 + (41 + y) * H160 + (41 + x)];
  float w0 = 0.f, w1 = 0.f, w2 = 0.f;
  for (int mv = 0; mv < 7; ++mv) {
    int dy = (y - mv) % 7; int gyy = y - dy;
    for (int mh = 0; mh < 7; ++mh) {
      int dx = (x - mh) % 7; int gxx = x - dx;
      int q = mv * 7 + mh;
      float v0, v1, v2;
      if (n == 0) { v0 = sv0; v1 = sv1; v2 = sv2; }
      else {
        int idx = fsi[(n - 1) * PG + gyy * GW + gxx];
        int fi = idx / IDX146; int rem = idx % IDX146;
        int pv = rem / 146, ph = rem % 146;
        int base = (4 + pv + dy) * H160 + (4 + ph + dx);
        v0 = seq[(0 * 7 + fi) * 25600 + base];
        v1 = seq[(1 * 7 + fi) * 25600 + base];
        v2 = seq[(2 * 7 + fi) * 25600 + base];
      }
      X[(size_t)(n * 150 + q * 3 + 0) * P66 + p] = v0;
      X[(size_t)(n * 150 + q * 3 + 1) * P66 + p] = v1;
      X[(size_t)(n * 150 + q * 3 + 2) * P66 + p] = v2;
      float e0 = v0 - sv0, e1 = v1 - sv1, e2 = v2 - sv2;
      w0 += e0 * e0; w1 += e1 * e1; w2 += e2 * e2;
    }
  }
  X[(size_t)(n * 150 + 147) * P66 + p] = w0 / 49.f;
  X[(size_t)(n * 150 + 148) * P66 + p] = w1 / 49.f;
  X[(size_t)(n * 150 + 149) * P66 + p] = w2 / 49.f;
}

// ---------------- k4a: reflect-pad 3 + grouped 7x7 conv (3-in -> 3-out per group) --
__global__ void k4a_vh(const float* __restrict__ in, const float* __restrict__ w,
                       float* __restrict__ out) {
  int g = blockIdx.y;                       // group, o0 = 3g
  int p = (int)blockIdx.x * 256 + threadIdx.x;
  if (p >= P66) return;
  int yo = p / 66, xo = p % 66;
  int o0 = g * 3;
  float a0 = 0.f, a1 = 0.f, a2 = 0.f;
#pragma unroll
  for (int ic = 0; ic < 3; ++ic) {
    const float* ip = in + (size_t)(o0 + ic) * P66;
    for (int ky = 0; ky < 7; ++ky) {
      int iy = yo + ky - 3; iy = iy < 0 ? -iy : (iy > 65 ? 130 - iy : iy);
      for (int kx = 0; kx < 7; ++kx) {
        int ix = xo + kx - 3; ix = ix < 0 ? -ix : (ix > 65 ? 130 - ix : ix);
        float v = ip[iy * 66 + ix];
        int wi = ky * 7 + kx;
        a0 = fmaf(v, w[(o0 + 0) * 147 + ic * 49 + wi], a0);
        a1 = fmaf(v, w[(o0 + 1) * 147 + ic * 49 + wi], a1);
        a2 = fmaf(v, w[(o0 + 2) * 147 + ic * 49 + wi], a2);
      }
    }
  }
  out[(size_t)(o0 + 0) * P66 + p] = a0;
  out[(size_t)(o0 + 1) * P66 + p] = a1;
  out[(size_t)(o0 + 2) * P66 + p] = a2;
}

// ---------------- k4b: 1x1 conv, groups of 150, 6 outputs/thread ----------------
__global__ void k4b_f(const float* __restrict__ in, const float* __restrict__ w,
                      float* __restrict__ out) {
  int ob = blockIdx.y * 6;
  int p = (int)blockIdx.x * 256 + threadIdx.x;
  if (p >= P66) return;
  int gb = (ob / 150) * 150;
  float a0=0.f,a1=0.f,a2=0.f,a3=0.f,a4=0.f,a5=0.f;
  const float* ip = in + (size_t)gb * P66 + p;
  const float* w0 = w + (size_t)ob * 150;
  for (int f = 0; f < 150; ++f) {
    float v = ip[(size_t)f * P66];
    a0 = fmaf(v, w0[f],        a0);
    a1 = fmaf(v, w0[150 + f],  a1);
    a2 = fmaf(v, w0[300 + f],  a2);
    a3 = fmaf(v, w0[450 + f],  a3);
    a4 = fmaf(v, w0[600 + f],  a4);
    a5 = fmaf(v, w0[750 + f],  a5);
  }
  out[(size_t)(ob + 0) * P66 + p] = a0;
  out[(size_t)(ob + 1) * P66 + p] = a1;
  out[(size_t)(ob + 2) * P66 + p] = a2;
  out[(size_t)(ob + 3) * P66 + p] = a3;
  out[(size_t)(ob + 4) * P66 + p] = a4;
  out[(size_t)(ob + 5) * P66 + p] = a5;
}

// ---------------- k4c: neighbor-mix 1x1 (groups of 150 feature channels) ----------
template<int NI, int NO>
__global__ void k4c_n(const float* __restrict__ in, const float* __restrict__ w,
                      const float* __restrict__ bias, float* __restrict__ out, int withbias) {
  int f = blockIdx.y;                       // 0..149
  int p = (int)blockIdx.x * 256 + threadIdx.x;
  if (p >= P66) return;
  float acc[NO];
#pragma unroll
  for (int j = 0; j < NO; ++j) acc[j] = 0.f;
#pragma unroll
  for (int nn = 0; nn < NI; ++nn) {
    float v = in[(size_t)(nn * 150 + f) * P66 + p];
#pragma unroll
    for (int j = 0; j < NO; ++j) acc[j] = fmaf(v, w[(f * NO + j) * NI + nn], acc[j]);
  }
#pragma unroll
  for (int j = 0; j < NO; ++j) {
    float r = acc[j];
    if (withbias) { r += bias[j * 150 + f]; r = r > 0.f ? r : 0.f; }
    out[(size_t)(j * 150 + f) * P66 + p] = r;
  }
}

// ---------------- BN (train-mode batch stats over 66x66) + relu, in place --------
__global__ void k_bn(float* __restrict__ x, const float* __restrict__ g,
                     const float* __restrict__ be) {
  int c = blockIdx.x;
  float* xp = x + (size_t)c * P66;
  __shared__ float red[256];
  int t = threadIdx.x;
  float s = 0.f;
  for (int p = t; p < P66; p += 256) s += xp[p];
  red[t] = s; __syncthreads();
  for (int off = 128; off > 0; off >>= 1) { if (t < off) red[t] += red[t + off]; __syncthreads(); }
  float m = red[0] / (float)P66;
  __syncthreads();
  float s2 = 0.f;
  for (int p = t; p < P66; p += 256) { float dd = xp[p] - m; s2 += dd * dd; }
  red[t] = s2; __syncthreads();
  for (int off = 128; off > 0; off >>= 1) { if (t < off) red[t] += red[t + off]; __syncthreads(); }
  float var = red[0] / (float)P66;
  float sc = g[c] / sqrtf(var + 1e-5f);
  float sh = be[c] - m * sc;
  for (int p = t; p < P66; p += 256) { float r = fmaf(xp[p], sc, sh); xp[p] = r > 0.f ? r : 0.f; }
}

// ---------------- final: w_f4 (150->3) + b4, out = valid - y ----------------------
__global__ void k_final(const float* __restrict__ in, const float* __restrict__ wf,
                        const float* __restrict__ b4, const float* __restrict__ seq,
                        float* __restrict__ out) {
  int p = (int)blockIdx.x * 256 + threadIdx.x;
  if (p >= P66) return;
  int yo = p / 66, xo = p % 66;
  float a0 = 0.f, a1 = 0.f, a2 = 0.f;
  for (int f = 0; f < 150; ++f) {
    float v = in[(size_t)f * P66 + p];
    a0 = fmaf(v, wf[f],       a0);
    a1 = fmaf(v, wf[150 + f], a1);
    a2 = fmaf(v, wf[300 + f], a2);
  }
  float y0 = a0 + b4[0], y1 = a1 + b4[1], y2 = a2 + b4[2];
  int vo = (47 + yo) * H160 + (47 + xo);
  out[0 * P66 + p] = seq[(0 * 7 + 3) * 25600 + vo] - y0;
  out[1 * P66 + p] = seq[(1 * 7 + 3) * 25600 + vo] - y1;
  out[2 * P66 + p] = seq[(2 * 7 + 3) * 25600 + vo] - y2;
}

extern "C" void kernel_launch(void* const* d_in, const int* in_sizes, int n_in,
                              void* d_out, int out_size, void* d_ws, size_t ws_size,
                              hipStream_t stream) {
  const float* seq   = (const float*)d_in[0];   // (1,3,7,160,160)
  const float* w_vh0 = (const float*)d_in[2];
  const float* w_f0  = (const float*)d_in[3];
  const float* w_n0  = (const float*)d_in[4];
  const float* w_vh1 = (const float*)d_in[5];
  const float* w_f1  = (const float*)d_in[6];
  const float* w_n1  = (const float*)d_in[7];
  const float* w_vh2 = (const float*)d_in[8];
  const float* w_f2  = (const float*)d_in[9];
  const float* w_n2  = (const float*)d_in[10];
  const float* w_vh3 = (const float*)d_in[11];
  const float* w_f3  = (const float*)d_in[12];
  const float* w_n3  = (const float*)d_in[13];
  const float* b0    = (const float*)d_in[14];
  const float* g1    = (const float*)d_in[15];
  const float* be1   = (const float*)d_in[16];
  const float* g2    = (const float*)d_in[17];
  const float* be2   = (const float*)d_in[18];
  const float* g3    = (const float*)d_in[19];
  const float* be3   = (const float*)d_in[20];
  const float* w_vh4 = (const float*)d_in[21];
  const float* w_f4  = (const float*)d_in[22];
  const float* b4    = (const float*)d_in[23];
  float* outp = (float*)d_out;

  // workspace layout: 93,041,472 B total (identical to round 2)
  float* fws  = (float*)d_ws;
  float* seqT = fws;                              // 537,600 f
  u64*   sk   = (u64*)(seqT + 537600);            // 21*14*5184 u64 = 12.19 MB
  float* X    = (float*)(sk + 1524096);           // 9,801,000 f
  float* A    = X + 9801000;                      // 9,801,000 f
  int*   fsi  = (int*)(A + 9801000);              // 72,576 int
  float* wsD  = X;                                // alias: 2625*5184 f spans X+A

  k0_transpose<<<dim3(160, 21), 160, 0, stream>>>(seq, seqT);
  k_init<<<(1524096 + 255) / 256, 256, 0, stream>>>(sk, 1524096);
  for (int c = 0; c < NCHUNK; ++c) {
    k1_dist<<<(CHUNK + 1) / 2, 128, 0, stream>>>(seqT, wsD, c * CHUNK);
    k2_topk<<<dim3(81, NSLOT), 256, 0, stream>>>(wsD, sk, c * CHUNK);
  }
  k_merge<<<81, 64, 0, stream>>>(sk, fsi);
  k3_layers<<<dim3(18, 15), 256, 0, stream>>>(seq, fsi, X);

  // L0: X -> A -> X -> A(1200) [+b0, relu]
  k4a_vh<<<dim3(18, 750), 256, 0, stream>>>(X, w_vh0, A);
  k4b_f <<<dim3(18, 375), 256, 0, stream>>>(A, w_f0, X);
  k4c_n<15, 8><<<dim3(18, 150), 256, 0, stream>>>(X, w_n0, b0, A, 1);
  // L1
  k4a_vh<<<dim3(18, 400), 256, 0, stream>>>(A, w_vh1, X);
  k4b_f <<<dim3(18, 200), 256, 0, stream>>>(X, w_f1, A);
  k4c_n<8, 4><<<dim3(18, 150), 256, 0, stream>>>(A, w_n1, nullptr, X, 0);
  k_bn<<<600, 256, 0, stream>>>(X, g1, be1);
  // L2
  k4a_vh<<<dim3(18, 200), 256, 0, stream>>>(X, w_vh2, A);
  k4b_f <<<dim3(18, 100), 256, 0, stream>>>(A, w_f2, X);
  k4c_n<4, 2><<<dim3(18, 150), 256, 0, stream>>>(X, w_n2, nullptr, A, 0);
  k_bn<<<300, 256, 0, stream>>>(A, g2, be2);
  // L3
  k4a_vh<<<dim3(18, 100), 256, 0, stream>>>(A, w_vh3, X);
  k4b_f <<<dim3(18, 50), 256, 0, stream>>>(X, w_f3, A);
  k4c_n<2, 1><<<dim3(18, 150), 256, 0, stream>>>(A, w_n3, nullptr, X, 0);
  k_bn<<<150, 256, 0, stream>>>(X, g3, be3);
  // L4
  k4a_vh<<<dim3(18, 50), 256, 0, stream>>>(X, w_vh4, A);
  k_final<<<18, 256, 0, stream>>>(A, w_f4, b4, seq, outp);
}

// Round 4
// 2258.065 us; speedup vs baseline: 1.6886x; 1.0741x over previous
//
#include <hip/hip_runtime.h>
#include <cstdint>
#include <cstddef>

// ---------------- constants ----------------
#define H160   160
#define HD     86          // h-74
#define GW     72          // grid width (72x72 points)
#define PG     5184        // 72*72
#define P66    4356        // 66*66
#define IDX146 21316       // 146*146
#define NVNH   5625        // 75*75
#define SELF_CAND 19687    // 3*5625 + 37*75 + 37
#define CHUNK  2625        // candidates per chunk (39375 = 15*2625)
#define NCHUNK 15
#define NSLOT  21
#define SLOTLEN 125
typedef unsigned long long u64;
struct F3 { float x, y, z; };

// ---------------- k0: transpose seq -> seqT3[t][x][y][c] (3-ch interleaved) ----
__global__ void k0_transpose(const float* __restrict__ seq, float* __restrict__ seqT3) {
  int t7 = blockIdx.y;           // frame 0..6
  int x  = blockIdx.x;           // col 0..159
  int y  = threadIdx.x;          // row 0..159
  int o = ((t7 * H160 + x) * H160 + y) * 3;
  seqT3[o + 0] = seq[(0 * 7 + t7) * 25600 + y * H160 + x];
  seqT3[o + 1] = seq[(1 * 7 + t7) * 25600 + y * H160 + x];
  seqT3[o + 2] = seq[(2 * 7 + t7) * 25600 + y * H160 + x];
}

// ---------------- init state keys to max ----------------
__global__ void k_init(u64* __restrict__ sk, int n) {
  int i = blockIdx.x * 256 + threadIdx.x;
  if (i < n) sk[i] = ~0ULL;
}

// ---------------- k1: per-candidate boxed distance field (bitwise-replicates
// numpy: d = mean_c((win-seq_n)^2); box15 via sequential fp32 cumsum diffs).
// Round 4: reverted to 1 candidate/block (R3's 2-per-block serial-doubled the
// dependent cumsum chains = regression); channel-interleaved loads (one addr
// chain, 12B contiguous per sample). Markstein div-by-3 kept (bit-exact). ----
__global__ __launch_bounds__(128) void k1_dist(const float* __restrict__ seqT3,
                                               float* __restrict__ wsD, int chunkBase) {
  __shared__ float cs[HD][87];   // row prefix sums, padded stride
  const float R3 = 0.33333334f;  // RN(1/3)
  int cand = chunkBase + (int)blockIdx.x;
  int ts = cand / NVNH;
  int rr = cand % NVNH;
  int vs = rr / 75;
  int hv = rr % 75;
  int t = threadIdx.x;
  if (t < HD) {
    const F3* pa = (const F3*)seqT3 + ((ts * H160 + hv) * H160 + (vs + t));
    const F3* pb = (const F3*)seqT3 + ((3  * H160 + 37) * H160 + (37 + t));
    float c0 = 0.f;
#pragma unroll 4
    for (int x = 0; x < HD; ++x) {
      F3 A = pa[x * H160];
      F3 B = pb[x * H160];
      float d0 = __fsub_rn(A.x, B.x);
      float d1 = __fsub_rn(A.y, B.y);
      float d2 = __fsub_rn(A.z, B.z);
      float s  = __fadd_rn(__fadd_rn(__fmul_rn(d0, d0), __fmul_rn(d1, d1)), __fmul_rn(d2, d2));
      float q0 = __fmul_rn(s, R3);
      float e  = __builtin_fmaf(-3.0f, q0, s);
      float dd = __builtin_fmaf(e, R3, q0);
      c0 = __fadd_rn(c0, dd);
      cs[t][x] = c0;
    }
  }
  __syncthreads();
  if (t < GW) {
    int jm = (t == 0) ? 0 : (t - 1);
    float cc = 0.f;
    float ring[16];
    float* D = wsD + (size_t)blockIdx.x * PG;
#pragma unroll
    for (int r = 0; r < HD; ++r) {
      float v = (t == 0) ? cs[r][14] : __fsub_rn(cs[r][t + 14], cs[r][jm]);
      cc = __fadd_rn(cc, v);
      ring[r & 15] = cc;
      if (r >= 14) {
        int gy = r - 14;
        float out = (gy == 0) ? cc : __fsub_rn(cc, ring[(gy - 1) & 15]);
        D[gy * GW + t] = out;
      }
    }
  }
}

// ---------------- k2: banked top-14 via u64 sort keys (unchanged from R3) ----
__global__ __launch_bounds__(256) void k2_topk(const float* __restrict__ wsD,
                                               u64* __restrict__ sk, int chunkBase) {
  __shared__ u64 lk[5][14][64];
  int tid = threadIdx.x;
  int w = tid >> 6, lane = tid & 63;
  int s = blockIdx.y;
  int pid = (int)blockIdx.x * 64 + lane;
  int st  = (w == 0) ? 96 : (w - 1) * 32;
  int cnt = (w == 0) ? 29 : 32;

  if (w == 0) {
#pragma unroll
    for (int k = 0; k < 14; ++k)
      lk[4][k][lane] = sk[(size_t)(s * 14 + k) * PG + pid];
  }
  float dv[32];
  const float* Dp = wsD + (size_t)(s * SLOTLEN + st) * PG + pid;
#pragma unroll
  for (int u = 0; u < 32; ++u)
    if (u < cnt) dv[u] = Dp[(size_t)u * PG];

  u64 key[14];
#pragma unroll
  for (int k = 0; k < 14; ++k) key[k] = ~0ULL;
  int cand0 = chunkBase + s * SLOTLEN + st;
#pragma unroll
  for (int u = 0; u < 32; ++u) {
    if (u < cnt) {
      int cand = cand0 + u;
      if (cand != SELF_CAND) {
        u64 nk = ((u64)__float_as_uint(dv[u]) << 32) | (unsigned)cand;
        if (nk < key[13]) {
#pragma unroll
          for (int j = 13; j >= 1; --j)
            key[j] = (nk < key[j - 1]) ? key[j - 1] : ((nk < key[j]) ? nk : key[j]);
          if (nk < key[0]) key[0] = nk;
        }
      }
    }
  }
#pragma unroll
  for (int k = 0; k < 14; ++k) lk[w][k][lane] = key[k];
  __syncthreads();
  if (w != 0) return;

  int h0 = 0, h1 = 0, h2 = 0, h3 = 0, h4 = 0;
  u64 a0 = lk[0][0][lane], a1 = lk[1][0][lane], a2 = lk[2][0][lane],
      a3 = lk[3][0][lane], a4 = lk[4][0][lane];
#pragma unroll
  for (int o = 0; o < 14; ++o) {
    u64 b01 = a0 < a1 ? a0 : a1; int j01 = a0 < a1 ? 0 : 1;
    u64 b23 = a2 < a3 ? a2 : a3; int j23 = a2 < a3 ? 2 : 3;
    u64 b03 = b01 < b23 ? b01 : b23; int j03 = b01 < b23 ? j01 : j23;
    u64 best = b03 < a4 ? b03 : a4; int bj = b03 < a4 ? j03 : 4;
    sk[(size_t)(s * 14 + o) * PG + pid] = best;
    h0 += (bj == 0); h1 += (bj == 1); h2 += (bj == 2); h3 += (bj == 3); h4 += (bj == 4);
    int c0 = h0 < 14 ? h0 : 13, c1 = h1 < 14 ? h1 : 13, c2 = h2 < 14 ? h2 : 13,
        c3 = h3 < 14 ? h3 : 13, c4 = h4 < 14 ? h4 : 13;
    a0 = lk[0][c0][lane]; if (h0 >= 14) a0 = ~0ULL;
    a1 = lk[1][c1][lane]; if (h1 >= 14) a1 = ~0ULL;
    a2 = lk[2][c2][lane]; if (h2 >= 14) a2 = ~0ULL;
    a3 = lk[3][c3][lane]; if (h3 >= 14) a3 = ~0ULL;
    a4 = lk[4][c4][lane]; if (h4 >= 14) a4 = ~0ULL;
  }
}

// ---------------- merge 21 slot lists -> final 14 indices ----------------
__global__ __launch_bounds__(64) void k_merge(const u64* __restrict__ sk,
                                              int* __restrict__ fsi) {
  int pid = (int)blockIdx.x * 64 + threadIdx.x;
  int gy = pid / GW, gx = pid % GW;
  int cur[NSLOT];
#pragma unroll
  for (int s = 0; s < NSLOT; ++s) cur[s] = 0;
  for (int o = 0; o < 14; ++o) {
    u64 bk = ~0ULL; int bs = 0;
#pragma unroll
    for (int s = 0; s < NSLOT; ++s) {
      int cc = cur[s] < 14 ? cur[s] : 13;
      u64 kk = sk[(size_t)(s * 14 + cc) * PG + pid];
      if (cur[s] >= 14) kk = ~0ULL;
      if (kk < bk) { bk = kk; bs = s; }
    }
#pragma unroll
    for (int s = 0; s < NSLOT; ++s) cur[s] += (bs == s) ? 1 : 0;
    int cand = (int)(unsigned)(bk & 0xffffffffULL);
    int ts = cand / NVNH;
    int rr = cand % NVNH;
    int vs = rr / 75, hv = rr % 75;
    fsi[o * PG + pid] = ts * IDX146 + (gy + vs) * 146 + (gx + hv);
  }
}

// ---------------- k3: build x_f = [layers(147), wts(3)] per neighbor slot ----------
__global__ void k3_layers(const float* __restrict__ seq, const int* __restrict__ fsi,
                          float* __restrict__ X) {
  int n = blockIdx.y;                       // 0..14
  int p = (int)blockIdx.x * 256 + threadIdx.x;
  if (p >= P66) return;
  int yo = p / 66, xo = p % 66;
  int y = yo + 6, x = xo + 6;
  float sv0 = seq[(0 * 7 + 3) * 25600 + (41 + y) * H160 + (41 + x)];
  float sv1 = seq[(1 * 7 + 3) * 25600 + (41 + y) * H160 + (41 + x)];
  float sv2 = seq[(2 * 7 + 3) * 25600 + (41 + y) * H160 + (41 + x)];
  float w0 = 0.f, w1 = 0.f, w2 = 0.f;
  for (int mv = 0; mv < 7; ++mv) {
    int dy = (y - mv) % 7; int gyy = y - dy;
    for (int mh = 0; mh < 7; ++mh) {
      int dx = (x - mh) % 7; int gxx = x - dx;
      int q = mv * 7 + mh;
      float v0, v1, v2;
      if (n == 0) { v0 = sv0; v1 = sv1; v2 = sv2; }
      else {
        int idx = fsi[(n - 1) * PG + gyy * GW + gxx];
        int fi = idx / IDX146; int rem = idx % IDX146;
        int pv = rem / 146, ph = rem % 146;
        int base = (4 + pv + dy) * H160 + (4 + ph + dx);
        v0 = seq[(0 * 7 + fi) * 25600 + base];
        v1 = seq[(1 * 7 + fi) * 25600 + base];
        v2 = seq[(2 * 7 + fi) * 25600 + base];
      }
      X[(size_t)(n * 150 + q * 3 + 0) * P66 + p] = v0;
      X[(size_t)(n * 150 + q * 3 + 1) * P66 + p] = v1;
      X[(size_t)(n * 150 + q * 3 + 2) * P66 + p] = v2;
      float e0 = v0 - sv0, e1 = v1 - sv1, e2 = v2 - sv2;
      w0 += e0 * e0; w1 += e1 * e1; w2 += e2 * e2;
    }
  }
  X[(size_t)(n * 150 + 147) * P66 + p] = w0 / 49.f;
  X[(size_t)(n * 150 + 148) * P66 + p] = w1 / 49.f;
  X[(size_t)(n * 150 + 149) * P66 + p] = w2 / 49.f;
}

// ---------------- k4a: reflect-pad 3 + grouped 7x7 conv.
// Round 4: 2 adjacent output px/thread, reflect indices hoisted, 8-wide
// register row shared by both px. FMA order per output unchanged (ic,ky,kx). --
#define NPAIR 2178   // P66/2
__global__ void k4a_vh(const float* __restrict__ in, const float* __restrict__ w,
                       float* __restrict__ out) {
  int g = blockIdx.y;                       // group, o0 = 3g
  int pp = (int)blockIdx.x * 256 + threadIdx.x;
  if (pp >= NPAIR) return;
  int yo = pp / 33, x0 = (pp % 33) * 2;
  int o0 = g * 3;
  int iy[7], ix[8];
#pragma unroll
  for (int k = 0; k < 7; ++k) { int v = yo + k - 3; iy[k] = v < 0 ? -v : (v > 65 ? 130 - v : v); }
#pragma unroll
  for (int k = 0; k < 8; ++k) { int v = x0 + k - 3; ix[k] = v < 0 ? -v : (v > 65 ? 130 - v : v); }
  float a0 = 0.f, a1 = 0.f, a2 = 0.f;    // px0, out-ch 0..2
  float b0 = 0.f, b1 = 0.f, b2 = 0.f;    // px1
#pragma unroll
  for (int ic = 0; ic < 3; ++ic) {
    const float* ip = in + (size_t)(o0 + ic) * P66;
    const float* wp = w + (size_t)o0 * 147 + ic * 49;
#pragma unroll
    for (int ky = 0; ky < 7; ++ky) {
      const float* row = ip + iy[ky] * 66;
      float r[8];
#pragma unroll
      for (int k = 0; k < 8; ++k) r[k] = row[ix[k]];
#pragma unroll
      for (int kx = 0; kx < 7; ++kx) {
        float wA = wp[ky * 7 + kx];
        float wB = wp[147 + ky * 7 + kx];
        float wC = wp[294 + ky * 7 + kx];
        float v0 = r[kx], v1 = r[kx + 1];
        a0 = fmaf(v0, wA, a0); b0 = fmaf(v1, wA, b0);
        a1 = fmaf(v0, wB, a1); b1 = fmaf(v1, wB, b1);
        a2 = fmaf(v0, wC, a2); b2 = fmaf(v1, wC, b2);
      }
    }
  }
  int px = yo * 66 + x0;
  *(float2*)&out[(size_t)(o0 + 0) * P66 + px] = make_float2(a0, b0);
  *(float2*)&out[(size_t)(o0 + 1) * P66 + px] = make_float2(a1, b1);
  *(float2*)&out[(size_t)(o0 + 2) * P66 + px] = make_float2(a2, b2);
}

// ---------------- k4b: 1x1 conv, groups of 150, 10 outputs/thread ----------------
__global__ void k4b_f(const float* __restrict__ in, const float* __restrict__ w,
                      float* __restrict__ out) {
  int ob = blockIdx.y * 10;
  int p = (int)blockIdx.x * 256 + threadIdx.x;
  if (p >= P66) return;
  int gb = (ob / 150) * 150;
  float acc[10];
#pragma unroll
  for (int j = 0; j < 10; ++j) acc[j] = 0.f;
  const float* ip = in + (size_t)gb * P66 + p;
  const float* w0 = w + (size_t)ob * 150;
  for (int f = 0; f < 150; ++f) {
    float v = ip[(size_t)f * P66];
#pragma unroll
    for (int j = 0; j < 10; ++j) acc[j] = fmaf(v, w0[j * 150 + f], acc[j]);
  }
#pragma unroll
  for (int j = 0; j < 10; ++j) out[(size_t)(ob + j) * P66 + p] = acc[j];
}

// ---------------- k4c: neighbor-mix 1x1 (groups of 150 feature channels) ----------
template<int NI, int NO>
__global__ void k4c_n(const float* __restrict__ in, const float* __restrict__ w,
                      const float* __restrict__ bias, float* __restrict__ out, int withbias) {
  int f = blockIdx.y;                       // 0..149
  int p = (int)blockIdx.x * 256 + threadIdx.x;
  if (p >= P66) return;
  float acc[NO];
#pragma unroll
  for (int j = 0; j < NO; ++j) acc[j] = 0.f;
#pragma unroll
  for (int nn = 0; nn < NI; ++nn) {
    float v = in[(size_t)(nn * 150 + f) * P66 + p];
#pragma unroll
    for (int j = 0; j < NO; ++j) acc[j] = fmaf(v, w[(f * NO + j) * NI + nn], acc[j]);
  }
#pragma unroll
  for (int j = 0; j < NO; ++j) {
    float r = acc[j];
    if (withbias) { r += bias[j * 150 + f]; r = r > 0.f ? r : 0.f; }
    out[(size_t)(j * 150 + f) * P66 + p] = r;
  }
}

// ---------------- BN (train-mode batch stats over 66x66) + relu, in place --------
__global__ void k_bn(float* __restrict__ x, const float* __restrict__ g,
                     const float* __restrict__ be) {
  int c = blockIdx.x;
  float* xp = x + (size_t)c * P66;
  __shared__ float red[256];
  int t = threadIdx.x;
  float s = 0.f;
  for (int p = t; p < P66; p += 256) s += xp[p];
  red[t] = s; __syncthreads();
  for (int off = 128; off > 0; off >>= 1) { if (t < off) red[t] += red[t + off]; __syncthreads(); }
  float m = red[0] / (float)P66;
  __syncthreads();
  float s2 = 0.f;
  for (int p = t; p < P66; p += 256) { float dd = xp[p] - m; s2 += dd * dd; }
  red[t] = s2; __syncthreads();
  for (int off = 128; off > 0; off >>= 1) { if (t < off) red[t] += red[t + off]; __syncthreads(); }
  float var = red[0] / (float)P66;
  float sc = g[c] / sqrtf(var + 1e-5f);
  float sh = be[c] - m * sc;
  for (int p = t; p < P66; p += 256) { float r = fmaf(xp[p], sc, sh); xp[p] = r > 0.f ? r : 0.f; }
}

// ---------------- final: w_f4 (150->3) + b4, out = valid - y ----------------------
__global__ void k_final(const float* __restrict__ in, const float* __restrict__ wf,
                        const float* __restrict__ b4, const float* __restrict__ seq,
                        float* __restrict__ out) {
  int p = (int)blockIdx.x * 256 + threadIdx.x;
  if (p >= P66) return;
  int yo = p / 66, xo = p % 66;
  float a0 = 0.f, a1 = 0.f, a2 = 0.f;
  for (int f = 0; f < 150; ++f) {
    float v = in[(size_t)f * P66 + p];
    a0 = fmaf(v, wf[f],       a0);
    a1 = fmaf(v, wf[150 + f], a1);
    a2 = fmaf(v, wf[300 + f], a2);
  }
  float y0 = a0 + b4[0], y1 = a1 + b4[1], y2 = a2 + b4[2];
  int vo = (47 + yo) * H160 + (47 + xo);
  out[0 * P66 + p] = seq[(0 * 7 + 3) * 25600 + vo] - y0;
  out[1 * P66 + p] = seq[(1 * 7 + 3) * 25600 + vo] - y1;
  out[2 * P66 + p] = seq[(2 * 7 + 3) * 25600 + vo] - y2;
}

extern "C" void kernel_launch(void* const* d_in, const int* in_sizes, int n_in,
                              void* d_out, int out_size, void* d_ws, size_t ws_size,
                              hipStream_t stream) {
  const float* seq   = (const float*)d_in[0];   // (1,3,7,160,160)
  const float* w_vh0 = (const float*)d_in[2];
  const float* w_f0  = (const float*)d_in[3];
  const float* w_n0  = (const float*)d_in[4];
  const float* w_vh1 = (const float*)d_in[5];
  const float* w_f1  = (const float*)d_in[6];
  const float* w_n1  = (const float*)d_in[7];
  const float* w_vh2 = (const float*)d_in[8];
  const float* w_f2  = (const float*)d_in[9];
  const float* w_n2  = (const float*)d_in[10];
  const float* w_vh3 = (const float*)d_in[11];
  const float* w_f3  = (const float*)d_in[12];
  const float* w_n3  = (const float*)d_in[13];
  const float* b0    = (const float*)d_in[14];
  const float* g1    = (const float*)d_in[15];
  const float* be1   = (const float*)d_in[16];
  const float* g2    = (const float*)d_in[17];
  const float* be2   = (const float*)d_in[18];
  const float* g3    = (const float*)d_in[19];
  const float* be3   = (const float*)d_in[20];
  const float* w_vh4 = (const float*)d_in[21];
  const float* w_f4  = (const float*)d_in[22];
  const float* b4    = (const float*)d_in[23];
  float* outp = (float*)d_out;

  // workspace layout: 93,041,472 B total (identical to R2/R3)
  float* fws   = (float*)d_ws;
  float* seqT3 = fws;                             // 537,600 f (interleaved now)
  u64*   sk    = (u64*)(seqT3 + 537600);          // 21*14*5184 u64
  float* X     = (float*)(sk + 1524096);          // 9,801,000 f
  float* A     = X + 9801000;                     // 9,801,000 f
  int*   fsi   = (int*)(A + 9801000);             // 72,576 int
  float* wsD   = X;                               // alias: 2625*5184 f spans X+A

  k0_transpose<<<dim3(160, 7), 160, 0, stream>>>(seq, seqT3);
  k_init<<<(1524096 + 255) / 256, 256, 0, stream>>>(sk, 1524096);
  for (int c = 0; c < NCHUNK; ++c) {
    k1_dist<<<CHUNK, 128, 0, stream>>>(seqT3, wsD, c * CHUNK);
    k2_topk<<<dim3(81, NSLOT), 256, 0, stream>>>(wsD, sk, c * CHUNK);
  }
  k_merge<<<81, 64, 0, stream>>>(sk, fsi);
  k3_layers<<<dim3(18, 15), 256, 0, stream>>>(seq, fsi, X);

  // L0: X -> A -> X -> A(1200) [+b0, relu]
  k4a_vh<<<dim3(9, 750), 256, 0, stream>>>(X, w_vh0, A);
  k4b_f <<<dim3(18, 225), 256, 0, stream>>>(A, w_f0, X);
  k4c_n<15, 8><<<dim3(18, 150), 256, 0, stream>>>(X, w_n0, b0, A, 1);
  // L1
  k4a_vh<<<dim3(9, 400), 256, 0, stream>>>(A, w_vh1, X);
  k4b_f <<<dim3(18, 120), 256, 0, stream>>>(X, w_f1, A);
  k4c_n<8, 4><<<dim3(18, 150), 256, 0, stream>>>(A, w_n1, nullptr, X, 0);
  k_bn<<<600, 256, 0, stream>>>(X, g1, be1);
  // L2
  k4a_vh<<<dim3(9, 200), 256, 0, stream>>>(X, w_vh2, A);
  k4b_f <<<dim3(18, 60), 256, 0, stream>>>(A, w_f2, X);
  k4c_n<4, 2><<<dim3(18, 150), 256, 0, stream>>>(X, w_n2, nullptr, A, 0);
  k_bn<<<300, 256, 0, stream>>>(A, g2, be2);
  // L3
  k4a_vh<<<dim3(9, 100), 256, 0, stream>>>(A, w_vh3, X);
  k4b_f <<<dim3(18, 30), 256, 0, stream>>>(X, w_f3, A);
  k4c_n<2, 1><<<dim3(18, 150), 256, 0, stream>>>(A, w_n3, nullptr, X, 0);
  k_bn<<<150, 256, 0, stream>>>(X, g3, be3);
  // L4
  k4a_vh<<<dim3(9, 50), 256, 0, stream>>>(X, w_vh4, A);
  k_final<<<18, 256, 0, stream>>>(A, w_f4, b4, seq, outp);
}